// Round 1
// baseline (319.249 us; speedup 1.0000x reference)
//
#include <hip/hip_runtime.h>
#include <hip/hip_bf16.h>

#define BB 64
#define CC 512
#define NPIX 784   // 28*28
#define KK 32

// ---------------------------------------------------------------------------
// Kernel 1: per-pixel scaled-distance softmax -> A[b,n,k]  (stored in d_ws)
// grid = B*NPIX/256 = 196 blocks, 256 threads, one thread per (b,n)
// ---------------------------------------------------------------------------
__global__ __launch_bounds__(256) void k_softmax_assign(
    const float* __restrict__ x,       // (B, C, N)
    const float* __restrict__ cw,      // (K, C)
    const float* __restrict__ scale,   // (K,)
    float* __restrict__ A)             // (B, N, K)
{
    // exactly 64 KB static LDS
    __shared__ __align__(16) float cw_lds[KK * CC];

    const int tid = threadIdx.x;

    // stage codewords into LDS (coalesced)
    for (int i = tid; i < KK * CC; i += 256) cw_lds[i] = cw[i];
    __syncthreads();

    const int flat = blockIdx.x * 256 + tid;   // B*NPIX = 50176 = 196*256 exactly
    const int b = flat / NPIX;
    const int n = flat - b * NPIX;

    const float* xp = x + (size_t)b * CC * NPIX + n;

    float acc[KK];
#pragma unroll
    for (int k = 0; k < KK; ++k) acc[k] = 0.f;
    float xsq = 0.f;

    for (int c = 0; c < CC; c += 4) {
        const float xv0 = xp[(size_t)(c + 0) * NPIX];
        const float xv1 = xp[(size_t)(c + 1) * NPIX];
        const float xv2 = xp[(size_t)(c + 2) * NPIX];
        const float xv3 = xp[(size_t)(c + 3) * NPIX];
        xsq += xv0 * xv0 + xv1 * xv1 + xv2 * xv2 + xv3 * xv3;
#pragma unroll
        for (int k = 0; k < KK; ++k) {
            const float4 cv = *(const float4*)&cw_lds[k * CC + c];
            acc[k] += xv0 * cv.x + xv1 * cv.y + xv2 * cv.z + xv3 * cv.w;
        }
    }

    // compute csq[k] AFTER the dot loop (cw_lds still valid), stash over cw_lds[0..31]
    __syncthreads();
    float csq_val = 0.f;
    if (tid < KK) {
        for (int c = 0; c < CC; ++c) {
            const float v = cw_lds[tid * CC + c];
            csq_val += v * v;
        }
    }
    __syncthreads();
    if (tid < KK) cw_lds[tid] = csq_val;
    __syncthreads();

    // dist_k = scale[k] * (xsq - 2*xc_k + csq_k); softmax over k
    float m = -1e30f;
#pragma unroll
    for (int k = 0; k < KK; ++k) {
        const float d = scale[k] * (xsq - 2.f * acc[k] + cw_lds[k]);
        acc[k] = d;
        m = fmaxf(m, d);
    }
    float ssum = 0.f;
#pragma unroll
    for (int k = 0; k < KK; ++k) {
        const float e = __expf(acc[k] - m);
        acc[k] = e;
        ssum += e;
    }
    const float inv = 1.f / ssum;

    float* Ap = A + (size_t)flat * KK;
#pragma unroll
    for (int k = 0; k < KK; k += 4) {
        float4 v = make_float4(acc[k] * inv, acc[k + 1] * inv, acc[k + 2] * inv, acc[k + 3] * inv);
        *(float4*)&Ap[k] = v;
    }
}

// ---------------------------------------------------------------------------
// Kernel 2: encoded[b,k,c] = sum_n A[b,n,k]*x[b,c,n] - (sum_n A[b,n,k])*cw[k,c]
// grid = (C/64, B) = (8, 64), 256 threads.
// thread t: c = c0 + (t&63), k in [ (t>>6)*8, +8 )
// ---------------------------------------------------------------------------
#define CT 64
#define NT 64

__global__ __launch_bounds__(256) void k_aggregate(
    const float* __restrict__ x,       // (B, C, N)
    const float* __restrict__ cw,      // (K, C)
    const float* __restrict__ A,       // (B, N, K)
    float* __restrict__ out)           // (B, K, C)
{
    __shared__ __align__(16) float xs[CT][NT + 1];  // +1 pad: kill 64-way bank conflict
    __shared__ __align__(16) float As[NT][KK];
    __shared__ float wpart[256];
    __shared__ float wsum[KK];

    const int t = threadIdx.x;
    const int b = blockIdx.y;
    const int c0 = blockIdx.x * CT;
    const int ci = t & 63;
    const int kg = t >> 6;   // 0..3  (constant within a wave -> As reads broadcast)

    float acc[8];
#pragma unroll
    for (int i = 0; i < 8; ++i) acc[i] = 0.f;
    float wp = 0.f;   // partial wsum for k = t&31 (constant: 256 % 32 == 0)

    const float* xb = x + (size_t)b * CC * NPIX;
    const float* Ab = A + (size_t)b * NPIX * KK;

    for (int n0 = 0; n0 < NPIX; n0 += NT) {
        __syncthreads();
        // stage x tile: 64c x 64n, 16 elems/thread, coalesced
#pragma unroll
        for (int j = 0; j < (CT * NT) / 256; ++j) {
            const int idx = t + j * 256;
            const int xci = idx >> 6, xni = idx & 63;
            const int n = n0 + xni;
            xs[xci][xni] = (n < NPIX) ? xb[(size_t)(c0 + xci) * NPIX + n] : 0.f;
        }
        // stage A tile: 64n x 32k, 8 elems/thread, coalesced; k = t&31 fixed
#pragma unroll
        for (int j = 0; j < (NT * KK) / 256; ++j) {
            const int idx = t + j * 256;
            const int ani = idx >> 5;
            const int n = n0 + ani;
            const float v = (n < NPIX) ? Ab[(size_t)n * KK + (idx & 31)] : 0.f;
            As[ani][idx & 31] = v;
            wp += v;
        }
        __syncthreads();

#pragma unroll 4
        for (int ni = 0; ni < NT; ++ni) {
            const float xv = xs[ci][ni];
            const float4 a0 = *(const float4*)&As[ni][kg * 8];
            const float4 a1 = *(const float4*)&As[ni][kg * 8 + 4];
            acc[0] += xv * a0.x; acc[1] += xv * a0.y;
            acc[2] += xv * a0.z; acc[3] += xv * a0.w;
            acc[4] += xv * a1.x; acc[5] += xv * a1.y;
            acc[6] += xv * a1.z; acc[7] += xv * a1.w;
        }
    }

    // reduce wsum: 8 partials per k
    wpart[t] = wp;
    __syncthreads();
    if (t < KK) {
        float s = 0.f;
#pragma unroll
        for (int j = 0; j < 8; ++j) s += wpart[t + j * 32];
        wsum[t] = s;
    }
    __syncthreads();

    const int c = c0 + ci;
#pragma unroll
    for (int kk = 0; kk < 8; ++kk) {
        const int k = kg * 8 + kk;
        out[((size_t)b * KK + k) * CC + c] = acc[kk] - wsum[k] * cw[k * CC + c];
    }
}

extern "C" void kernel_launch(void* const* d_in, const int* in_sizes, int n_in,
                              void* d_out, int out_size, void* d_ws, size_t ws_size,
                              hipStream_t stream) {
    const float* x     = (const float*)d_in[0];   // (64, 512, 28, 28)
    const float* cw    = (const float*)d_in[1];   // (32, 512)
    const float* scale = (const float*)d_in[2];   // (32,)
    float* out = (float*)d_out;                   // (64, 32, 512)
    float* A   = (float*)d_ws;                    // (64, 784, 32) = 6.4 MB

    k_softmax_assign<<<dim3((BB * NPIX) / 256), dim3(256), 0, stream>>>(x, cw, scale, A);
    k_aggregate<<<dim3(CC / CT, BB), dim3(256), 0, stream>>>(x, cw, A, out);
}